// Round 11
// baseline (229.162 us; speedup 1.0000x reference)
//
#include <hip/hip_runtime.h>
#include <hip/hip_bf16.h>

#define L_SEQ  4096
#define NBATCH 8
#define DMODEL 1024
#define DRED   32
#define NPAIR  496
#define PK     512                 // K padded to 512 for MFMA
#define MROWS  (NBATCH * L_SEQ)    // 32768

typedef __bf16 bf16x8 __attribute__((ext_vector_type(8)));
typedef float  f32x4  __attribute__((ext_vector_type(4)));
typedef unsigned short u16x8 __attribute__((ext_vector_type(8)));

typedef const __attribute__((address_space(1))) void g_void;
typedef __attribute__((address_space(3))) void lds_void;

// (i,j) pair table, np.triu_indices(32, k=1) order; pads use i=j=0 -> value 0.
struct PairTab { unsigned short v[512]; };
static constexpr PairTab make_tab() {
  PairTab t{};
  int p = 0;
  for (int i = 0; i < DRED; ++i)
    for (int j = i + 1; j < DRED; ++j) { t.v[p] = (unsigned short)(i | (j << 8)); ++p; }
  for (; p < 512; ++p) t.v[p] = 0;
  return t;
}
__constant__ PairTab PTAB = make_tab();

// ---- merged prep: blocks 0-127: Wt[n][k] = bf16(W_plu_w[k][n]) (pad k>=496);
//      blocks 128-191: Bh/Bl hi-lo split of W_red^T (512 elems/block) ----
__global__ __launch_bounds__(256) void kprep(const float* __restrict__ Wplu,
                                             __bf16* __restrict__ Wt,
                                             const float* __restrict__ Wred,
                                             __bf16* __restrict__ Bh,
                                             __bf16* __restrict__ Bl) {
  const int tid = threadIdx.x;
  if (blockIdx.x < 128) {
    __shared__ float tile[64][65];          // +1 pad: conflict-free transpose
    const int k0 = (blockIdx.x & 7) << 6;   // 8 k-tiles
    const int n0 = (blockIdx.x >> 3) << 6;  // 16 n-tiles
#pragma unroll
    for (int it = 0; it < 16; ++it) {
      int e = it * 256 + tid;
      int i = e >> 6, j = e & 63;
      float v = 0.f;
      if (k0 + i < NPAIR) v = Wplu[(size_t)(k0 + i) * DMODEL + n0 + j];
      tile[i][j] = v;
    }
    __syncthreads();
#pragma unroll
    for (int it = 0; it < 16; ++it) {
      int e = it * 256 + tid;
      int rn = e >> 6, ck = e & 63;
      Wt[(size_t)(n0 + rn) * PK + k0 + ck] = (__bf16)tile[ck][rn];
    }
  } else {
#pragma unroll
    for (int e = 0; e < 2; ++e) {
      int idx = (blockIdx.x - 128) * 512 + e * 256 + tid;  // 64*512 = 32768
      int n = idx >> 10, k = idx & 1023;
      float v = Wred[k * DRED + n];
      __bf16 hh = (__bf16)v;
      Bh[idx] = hh;
      Bl[idx] = (__bf16)(v - (float)hh);
    }
  }
}

// ---- z = h @ W_red + b via MFMA, RNE hi/lo bf16 split (~f32 precision) ----
// M=32 rows/wave: each B-fragment feeds 2 row-groups (12 MFMA / 4 B-loads).
__global__ __launch_bounds__(256) void kz(const float* __restrict__ h,
                                          const __bf16* __restrict__ Bh,
                                          const __bf16* __restrict__ Bl,
                                          const float* __restrict__ Wrb,
                                          float* __restrict__ z) {
  const int w = threadIdx.x >> 6;
  const int lane = threadIdx.x & 63;
  const int l15 = lane & 15, hi = lane >> 4;
  const int m0 = blockIdx.x * 128 + w * 32;   // wave owns 32 rows
  f32x4 acc[2][2] = {};                       // [row-group][n-half]
  const float* hp0 = h + (size_t)(m0 + l15) * DMODEL + hi * 8;
  const float* hp1 = hp0 + (size_t)16 * DMODEL;
  const __bf16* bh0 = Bh + (size_t)l15 * DMODEL + hi * 8;
  const __bf16* bh1 = bh0 + 16 * DMODEL;
  const __bf16* bl0 = Bl + (size_t)l15 * DMODEL + hi * 8;
  const __bf16* bl1 = bl0 + 16 * DMODEL;
#pragma unroll 4
  for (int kt = 0; kt < 32; ++kt) {           // K = 1024, 32 per MFMA
    const int ko = kt * 32;
    bf16x8 ah[2], al[2];
#pragma unroll
    for (int rg = 0; rg < 2; ++rg) {
      const float* hp = rg ? hp1 : hp0;
      f32x4 v0 = *(const f32x4*)(hp + ko);
      f32x4 v1 = *(const f32x4*)(hp + ko + 4);
#pragma unroll
      for (int q = 0; q < 4; ++q) {
        float f0 = v0[q], f1 = v1[q];
        __bf16 h0 = (__bf16)f0, h1 = (__bf16)f1;
        ah[rg][q] = h0;     ah[rg][q + 4] = h1;
        al[rg][q] = (__bf16)(f0 - (float)h0);
        al[rg][q + 4] = (__bf16)(f1 - (float)h1);
      }
    }
    bf16x8 b0h = *(const bf16x8*)(bh0 + ko);
    bf16x8 b1h = *(const bf16x8*)(bh1 + ko);
    bf16x8 b0l = *(const bf16x8*)(bl0 + ko);
    bf16x8 b1l = *(const bf16x8*)(bl1 + ko);
#pragma unroll
    for (int rg = 0; rg < 2; ++rg) {
      acc[rg][0] = __builtin_amdgcn_mfma_f32_16x16x32_bf16(ah[rg], b0h, acc[rg][0], 0, 0, 0);
      acc[rg][1] = __builtin_amdgcn_mfma_f32_16x16x32_bf16(ah[rg], b1h, acc[rg][1], 0, 0, 0);
      acc[rg][0] = __builtin_amdgcn_mfma_f32_16x16x32_bf16(al[rg], b0h, acc[rg][0], 0, 0, 0);
      acc[rg][1] = __builtin_amdgcn_mfma_f32_16x16x32_bf16(al[rg], b1h, acc[rg][1], 0, 0, 0);
      acc[rg][0] = __builtin_amdgcn_mfma_f32_16x16x32_bf16(ah[rg], b0l, acc[rg][0], 0, 0, 0);
      acc[rg][1] = __builtin_amdgcn_mfma_f32_16x16x32_bf16(ah[rg], b1l, acc[rg][1], 0, 0, 0);
    }
  }
#pragma unroll
  for (int rg = 0; rg < 2; ++rg)
#pragma unroll
    for (int nt = 0; nt < 2; ++nt) {
      const float bias = Wrb[nt * 16 + l15];
#pragma unroll
      for (int q = 0; q < 4; ++q) {
        // C/D layout: col = lane&15, row = (lane>>4)*4 + q
        z[(size_t)(m0 + rg * 16 + hi * 4 + q) * DRED + nt * 16 + l15]
            = acc[rg][nt][q] + bias;
      }
    }
}

// ---- p_hat rows (bf16, [MROWS][512]); one wave per row ----
__global__ __launch_bounds__(256) void kpairs(const float* __restrict__ z,
                                              const int* __restrict__ dOff,
                                              __bf16* __restrict__ A) {
  const int delta = *dOff;
  const int lane = threadIdx.x & 63;
  const int m = blockIdx.x * 4 + (threadIdx.x >> 6);
  const int t = m & (L_SEQ - 1);
  __bf16* arow = A + (size_t)m * PK;
  if (t < delta) {                            // reference leaves these rows 0
    u16x8 zz = {0, 0, 0, 0, 0, 0, 0, 0};
    *(u16x8*)(arow + lane * 8) = zz;
    return;
  }
  const float zt  = z[(size_t)m * DRED + (lane & 31)];
  const float ztd = z[(size_t)(m - delta) * DRED + (lane & 31)];
  const u16x8 tab = *(const u16x8*)(PTAB.v + lane * 8);
  float p[8];
  float s = 0.f;
#pragma unroll
  for (int q = 0; q < 8; ++q) {
    const int i = tab[q] & 255;
    const int j = tab[q] >> 8;
    float zti  = __shfl(zt,  i, 64);
    float ztdj = __shfl(ztd, j, 64);
    float ztj  = __shfl(zt,  j, 64);
    float ztdi = __shfl(ztd, i, 64);
    p[q] = fmaf(zti, ztdj, -(ztj * ztdi));
    s = fmaf(p[q], p[q], s);
  }
#pragma unroll
  for (int off = 1; off < 64; off <<= 1) s += __shfl_xor(s, off, 64);
  const float rcp = 1.f / fmaxf(sqrtf(s), 1e-8f);
  bf16x8 o;
#pragma unroll
  for (int q = 0; q < 8; ++q) o[q] = (__bf16)(p[q] * rcp);
  *(bf16x8*)(arow + lane * 8) = o;
}

// ---- g = p_hat @ W_plu + bias; rows t<delta forced to 0 ----
// DIAGNOSTIC ROUND: grid x4 — rep = blockIdx>>11 discarded, all 4 replicas
// compute/write byte-identical tiles (same-value aligned stores: benign,
// deterministic). Makes kgemm ~4x55 us -> top-1 in rocprof WITH counters.
// Kernel body identical to R10 (512 thr, BK=64 dbuf, counted vmcnt).
__global__ __launch_bounds__(512) void kgemm(const __bf16* __restrict__ A,
                                             const __bf16* __restrict__ Bt,
                                             const float* __restrict__ bias,
                                             const int* __restrict__ dOff,
                                             float* __restrict__ out) {
  __shared__ __bf16 Asm[2][128 * 64];         // 16 KB per buf
  __shared__ __bf16 Bsm[2][128 * 64];
  const int delta = *dOff;
  // bijective XCD-chunked swizzle on the inner 2048 (2048 % 8 == 0)
  const int d = blockIdx.x & 2047;            // replica index >>11 discarded
  const int lb = ((d & 7) << 8) + (d >> 3);
  const int bm = lb >> 3, bn = lb & 7;
  const int m0 = bm << 7, n0 = bn << 7;
  const int t = threadIdx.x;
  const int wv = t >> 6, lane = t & 63;
  const int l15 = lane & 15, hi = lane >> 4;
  const int wm = (wv >> 2) << 6, wn = (wv & 3) << 5;   // wave's 64x32 sub-tile

  f32x4 acc[4][2] = {};

  const __bf16* gA[2];
  const __bf16* gB[2];
  int cb[2];
#pragma unroll
  for (int it = 0; it < 2; ++it) {
    const int c = it * 512 + t;
    const int row = c >> 3, j = t & 7;
    const int jg = j ^ (row & 7);
    gA[it] = A  + (size_t)(m0 + row) * PK + jg * 8;
    gB[it] = Bt + (size_t)(n0 + row) * PK + jg * 8;
    cb[it] = (it * 512 + (wv << 6)) * 16;      // wave-uniform LDS base
  }

#define STAGE(buf, kt) do {                                                      \
    const int _ko = (kt) * 64;                                                   \
    _Pragma("unroll")                                                            \
    for (int _it = 0; _it < 2; ++_it) {                                          \
      __builtin_amdgcn_global_load_lds((g_void*)(gA[_it] + _ko),                 \
          (lds_void*)((char*)Asm[buf] + cb[_it]), 16, 0, 0);                     \
      __builtin_amdgcn_global_load_lds((g_void*)(gB[_it] + _ko),                 \
          (lds_void*)((char*)Bsm[buf] + cb[_it]), 16, 0, 0);                     \
    }                                                                            \
  } while (0)

  STAGE(0, 0);                                // 4 loads in flight
#pragma unroll
  for (int kt = 0; kt < 8; ++kt) {            // K = 512, BK = 64
    const int buf = kt & 1;
    if (kt < 7) STAGE(buf ^ 1, kt + 1);       // +4 -> 8 in flight
    if (kt < 7) asm volatile("s_waitcnt vmcnt(4)" ::: "memory");
    else        asm volatile("s_waitcnt vmcnt(0)" ::: "memory");
    __builtin_amdgcn_s_barrier();             // raw: no vmcnt drain
    __builtin_amdgcn_sched_barrier(0);        // pin LDS reads below barrier
#pragma unroll
    for (int kh = 0; kh < 2; ++kh) {
      bf16x8 afr[4], bfr[2];
#pragma unroll
      for (int mi = 0; mi < 4; ++mi) {
        const int row = wm + mi * 16 + l15;
        const int jj = (kh * 4 + hi) ^ (row & 7);
        afr[mi] = *(const bf16x8*)((const char*)Asm[buf] + row * 128 + jj * 16);
      }
#pragma unroll
      for (int ni = 0; ni < 2; ++ni) {
        const int row = wn + ni * 16 + l15;
        const int jj = (kh * 4 + hi) ^ (row & 7);
        bfr[ni] = *(const bf16x8*)((const char*)Bsm[buf] + row * 128 + jj * 16);
      }
#pragma unroll
      for (int mi = 0; mi < 4; ++mi)
#pragma unroll
        for (int ni = 0; ni < 2; ++ni)
          acc[mi][ni] = __builtin_amdgcn_mfma_f32_16x16x32_bf16(afr[mi], bfr[ni],
                                                                acc[mi][ni], 0, 0, 0);
    }
    if (kt < 7) {
      asm volatile("" ::: "memory");
      __builtin_amdgcn_s_barrier();
    }
  }
#undef STAGE

  float bv[2];
#pragma unroll
  for (int ni = 0; ni < 2; ++ni) bv[ni] = bias[n0 + wn + ni * 16 + l15];
#pragma unroll
  for (int mi = 0; mi < 4; ++mi)
#pragma unroll
    for (int ni = 0; ni < 2; ++ni)
#pragma unroll
      for (int q = 0; q < 4; ++q) {
        // C/D layout: col = lane&15, row = (lane>>4)*4 + q  [m89/m91]
        const int row = m0 + wm + mi * 16 + hi * 4 + q;
        const int col = n0 + wn + ni * 16 + l15;
        float v = acc[mi][ni][q] + bv[ni];
        if ((row & (L_SEQ - 1)) < delta) v = 0.f;
        out[(size_t)row * DMODEL + col] = v;
      }
}

extern "C" void kernel_launch(void* const* d_in, const int* in_sizes, int n_in,
                              void* d_out, int out_size, void* d_ws, size_t ws_size,
                              hipStream_t stream) {
  const float* h    = (const float*)d_in[0];
  const int*   woff = (const int*)d_in[1];
  const float* Wred = (const float*)d_in[2];
  const float* Wrb  = (const float*)d_in[3];
  const float* Wplu = (const float*)d_in[4];
  const float* Wpb  = (const float*)d_in[5];
  float* out = (float*)d_out;

  char* ws = (char*)d_ws;
  float*  z   = (float*)ws;                                    // 4 MB
  __bf16* Aph = (__bf16*)(ws + (4u << 20));                    // 32 MB
  __bf16* Wt  = (__bf16*)(ws + (36u << 20));                   // 1 MB
  __bf16* Bh  = (__bf16*)(ws + (37u << 20));                   // 64 KB
  __bf16* Bl  = (__bf16*)(ws + (37u << 20) + (64u << 10));     // 64 KB

  hipLaunchKernelGGL(kprep,  dim3(192),         dim3(256), 0, stream, Wplu, Wt, Wred, Bh, Bl);
  hipLaunchKernelGGL(kz,     dim3(MROWS / 128), dim3(256), 0, stream, h, Bh, Bl, Wrb, z);
  hipLaunchKernelGGL(kpairs, dim3(MROWS / 4),   dim3(256), 0, stream, z, woff, Aph);
  // DIAGNOSTIC: grid x4 (see kgemm comment) — reverts next round.
  hipLaunchKernelGGL(kgemm,  dim3(2048 * 4),    dim3(512), 0, stream, Aph, Wt, Wpb, woff, out);
}

// Round 14
// 116.291 us; speedup vs baseline: 1.9706x; 1.9706x over previous
//
#include <hip/hip_runtime.h>
#include <hip/hip_bf16.h>

#define L_SEQ  4096
#define NBATCH 8
#define DMODEL 1024
#define DRED   32
#define NPAIR  496
#define PK     512                 // K padded to 512 for MFMA
#define MROWS  (NBATCH * L_SEQ)    // 32768

typedef __bf16 bf16x8 __attribute__((ext_vector_type(8)));
typedef float  f32x4  __attribute__((ext_vector_type(4)));
typedef unsigned short u16x8 __attribute__((ext_vector_type(8)));

typedef const __attribute__((address_space(1))) void g_void;
typedef __attribute__((address_space(3))) void lds_void;

// (i,j) pair table, np.triu_indices(32, k=1) order; pads use i=j=0 -> value 0.
struct PairTab { unsigned short v[512]; };
static constexpr PairTab make_tab() {
  PairTab t{};
  int p = 0;
  for (int i = 0; i < DRED; ++i)
    for (int j = i + 1; j < DRED; ++j) { t.v[p] = (unsigned short)(i | (j << 8)); ++p; }
  for (; p < 512; ++p) t.v[p] = 0;
  return t;
}
__constant__ PairTab PTAB = make_tab();

// ---- merged prep: blocks 0-127: Wt[n][k] = bf16(W_plu_w[k][n]) (pad k>=496);
//      blocks 128-191: Bh/Bl hi-lo split of W_red^T (512 elems/block) ----
__global__ __launch_bounds__(256) void kprep(const float* __restrict__ Wplu,
                                             __bf16* __restrict__ Wt,
                                             const float* __restrict__ Wred,
                                             __bf16* __restrict__ Bh,
                                             __bf16* __restrict__ Bl) {
  const int tid = threadIdx.x;
  if (blockIdx.x < 128) {
    __shared__ float tile[64][65];          // +1 pad: conflict-free transpose
    const int k0 = (blockIdx.x & 7) << 6;   // 8 k-tiles
    const int n0 = (blockIdx.x >> 3) << 6;  // 16 n-tiles
#pragma unroll
    for (int it = 0; it < 16; ++it) {
      int e = it * 256 + tid;
      int i = e >> 6, j = e & 63;
      float v = 0.f;
      if (k0 + i < NPAIR) v = Wplu[(size_t)(k0 + i) * DMODEL + n0 + j];
      tile[i][j] = v;
    }
    __syncthreads();
#pragma unroll
    for (int it = 0; it < 16; ++it) {
      int e = it * 256 + tid;
      int rn = e >> 6, ck = e & 63;
      Wt[(size_t)(n0 + rn) * PK + k0 + ck] = (__bf16)tile[ck][rn];
    }
  } else {
#pragma unroll
    for (int e = 0; e < 2; ++e) {
      int idx = (blockIdx.x - 128) * 512 + e * 256 + tid;  // 64*512 = 32768
      int n = idx >> 10, k = idx & 1023;
      float v = Wred[k * DRED + n];
      __bf16 hh = (__bf16)v;
      Bh[idx] = hh;
      Bl[idx] = (__bf16)(v - (float)hh);
    }
  }
}

// ---- z = h @ W_red + b via MFMA, RNE hi/lo bf16 split (~f32 precision) ----
// M=32 rows/wave: each B-fragment feeds 2 row-groups (12 MFMA / 4 B-loads).
__global__ __launch_bounds__(256) void kz(const float* __restrict__ h,
                                          const __bf16* __restrict__ Bh,
                                          const __bf16* __restrict__ Bl,
                                          const float* __restrict__ Wrb,
                                          float* __restrict__ z) {
  const int w = threadIdx.x >> 6;
  const int lane = threadIdx.x & 63;
  const int l15 = lane & 15, hi = lane >> 4;
  const int m0 = blockIdx.x * 128 + w * 32;   // wave owns 32 rows
  f32x4 acc[2][2] = {};                       // [row-group][n-half]
  const float* hp0 = h + (size_t)(m0 + l15) * DMODEL + hi * 8;
  const float* hp1 = hp0 + (size_t)16 * DMODEL;
  const __bf16* bh0 = Bh + (size_t)l15 * DMODEL + hi * 8;
  const __bf16* bh1 = bh0 + 16 * DMODEL;
  const __bf16* bl0 = Bl + (size_t)l15 * DMODEL + hi * 8;
  const __bf16* bl1 = bl0 + 16 * DMODEL;
#pragma unroll 4
  for (int kt = 0; kt < 32; ++kt) {           // K = 1024, 32 per MFMA
    const int ko = kt * 32;
    bf16x8 ah[2], al[2];
#pragma unroll
    for (int rg = 0; rg < 2; ++rg) {
      const float* hp = rg ? hp1 : hp0;
      f32x4 v0 = *(const f32x4*)(hp + ko);
      f32x4 v1 = *(const f32x4*)(hp + ko + 4);
#pragma unroll
      for (int q = 0; q < 4; ++q) {
        float f0 = v0[q], f1 = v1[q];
        __bf16 h0 = (__bf16)f0, h1 = (__bf16)f1;
        ah[rg][q] = h0;     ah[rg][q + 4] = h1;
        al[rg][q] = (__bf16)(f0 - (float)h0);
        al[rg][q + 4] = (__bf16)(f1 - (float)h1);
      }
    }
    bf16x8 b0h = *(const bf16x8*)(bh0 + ko);
    bf16x8 b1h = *(const bf16x8*)(bh1 + ko);
    bf16x8 b0l = *(const bf16x8*)(bl0 + ko);
    bf16x8 b1l = *(const bf16x8*)(bl1 + ko);
#pragma unroll
    for (int rg = 0; rg < 2; ++rg) {
      acc[rg][0] = __builtin_amdgcn_mfma_f32_16x16x32_bf16(ah[rg], b0h, acc[rg][0], 0, 0, 0);
      acc[rg][1] = __builtin_amdgcn_mfma_f32_16x16x32_bf16(ah[rg], b1h, acc[rg][1], 0, 0, 0);
      acc[rg][0] = __builtin_amdgcn_mfma_f32_16x16x32_bf16(al[rg], b0h, acc[rg][0], 0, 0, 0);
      acc[rg][1] = __builtin_amdgcn_mfma_f32_16x16x32_bf16(al[rg], b1h, acc[rg][1], 0, 0, 0);
      acc[rg][0] = __builtin_amdgcn_mfma_f32_16x16x32_bf16(ah[rg], b0l, acc[rg][0], 0, 0, 0);
      acc[rg][1] = __builtin_amdgcn_mfma_f32_16x16x32_bf16(ah[rg], b1l, acc[rg][1], 0, 0, 0);
    }
  }
#pragma unroll
  for (int rg = 0; rg < 2; ++rg)
#pragma unroll
    for (int nt = 0; nt < 2; ++nt) {
      const float bias = Wrb[nt * 16 + l15];
#pragma unroll
      for (int q = 0; q < 4; ++q) {
        // C/D layout: col = lane&15, row = (lane>>4)*4 + q
        z[(size_t)(m0 + rg * 16 + hi * 4 + q) * DRED + nt * 16 + l15]
            = acc[rg][nt][q] + bias;
      }
    }
}

// ---- p_hat rows (bf16, [MROWS][512]); one wave per row ----
__global__ __launch_bounds__(256) void kpairs(const float* __restrict__ z,
                                              const int* __restrict__ dOff,
                                              __bf16* __restrict__ A) {
  const int delta = *dOff;
  const int lane = threadIdx.x & 63;
  const int m = blockIdx.x * 4 + (threadIdx.x >> 6);
  const int t = m & (L_SEQ - 1);
  __bf16* arow = A + (size_t)m * PK;
  if (t < delta) {                            // reference leaves these rows 0
    u16x8 zz = {0, 0, 0, 0, 0, 0, 0, 0};
    *(u16x8*)(arow + lane * 8) = zz;
    return;
  }
  const float zt  = z[(size_t)m * DRED + (lane & 31)];
  const float ztd = z[(size_t)(m - delta) * DRED + (lane & 31)];
  const u16x8 tab = *(const u16x8*)(PTAB.v + lane * 8);
  float p[8];
  float s = 0.f;
#pragma unroll
  for (int q = 0; q < 8; ++q) {
    const int i = tab[q] & 255;
    const int j = tab[q] >> 8;
    float zti  = __shfl(zt,  i, 64);
    float ztdj = __shfl(ztd, j, 64);
    float ztj  = __shfl(zt,  j, 64);
    float ztdi = __shfl(ztd, i, 64);
    p[q] = fmaf(zti, ztdj, -(ztj * ztdi));
    s = fmaf(p[q], p[q], s);
  }
#pragma unroll
  for (int off = 1; off < 64; off <<= 1) s += __shfl_xor(s, off, 64);
  const float rcp = 1.f / fmaxf(sqrtf(s), 1e-8f);
  bf16x8 o;
#pragma unroll
  for (int q = 0; q < 8; ++q) o[q] = (__bf16)(p[q] * rcp);
  *(bf16x8*)(arow + lane * 8) = o;
}

// ---- g = p_hat @ W_plu + bias; rows t<delta forced to 0 ----
// EXACT R7 form (validated + replay-clean in rounds 7/8/9): 4 waves, 128x128
// tile, BK=64 dbuf, counted vmcnt + raw s_barrier, scattered 4B epilogue.
__global__ __launch_bounds__(256) void kgemm(const __bf16* __restrict__ A,
                                             const __bf16* __restrict__ Bt,
                                             const float* __restrict__ bias,
                                             const int* __restrict__ dOff,
                                             float* __restrict__ out) {
  __shared__ __bf16 Asm[2][128 * 64];         // 16 KB per buf
  __shared__ __bf16 Bsm[2][128 * 64];
  const int delta = *dOff;
  // bijective XCD-chunked swizzle (2048 blocks % 8 XCDs == 0)
  const int d = blockIdx.x;
  const int lb = ((d & 7) << 8) + (d >> 3);
  const int bm = lb >> 3, bn = lb & 7;
  const int m0 = bm << 7, n0 = bn << 7;
  const int t = threadIdx.x;
  const int wv = t >> 6, lane = t & 63;
  const int l15 = lane & 15, hi = lane >> 4;
  const int wm = (wv >> 1) << 6, wn = (wv & 1) << 6;   // wave's 64x64 sub-tile

  f32x4 acc[4][4] = {};

  const __bf16* gA[4];
  const __bf16* gB[4];
  int cb[4];
#pragma unroll
  for (int it = 0; it < 4; ++it) {
    const int c = it * 256 + t;
    const int row = c >> 3, j = t & 7;
    const int jg = j ^ (row & 7);
    gA[it] = A  + (size_t)(m0 + row) * PK + jg * 8;
    gB[it] = Bt + (size_t)(n0 + row) * PK + jg * 8;
    cb[it] = (it * 256 + (wv << 6)) * 16;      // wave-uniform LDS base
  }

#define STAGE(buf, kt) do {                                                      \
    const int _ko = (kt) * 64;                                                   \
    _Pragma("unroll")                                                            \
    for (int _it = 0; _it < 4; ++_it) {                                          \
      __builtin_amdgcn_global_load_lds((g_void*)(gA[_it] + _ko),                 \
          (lds_void*)((char*)Asm[buf] + cb[_it]), 16, 0, 0);                     \
      __builtin_amdgcn_global_load_lds((g_void*)(gB[_it] + _ko),                 \
          (lds_void*)((char*)Bsm[buf] + cb[_it]), 16, 0, 0);                     \
    }                                                                            \
  } while (0)

  STAGE(0, 0);                                // 8 loads in flight
#pragma unroll
  for (int kt = 0; kt < 8; ++kt) {            // K = 512, BK = 64
    const int buf = kt & 1;
    if (kt < 7) STAGE(buf ^ 1, kt + 1);       // +8 -> 16 in flight
    if (kt < 7) asm volatile("s_waitcnt vmcnt(8)" ::: "memory");
    else        asm volatile("s_waitcnt vmcnt(0)" ::: "memory");
    __builtin_amdgcn_s_barrier();             // raw: no vmcnt drain
    __builtin_amdgcn_sched_barrier(0);        // pin LDS reads below barrier
#pragma unroll
    for (int kh = 0; kh < 2; ++kh) {
      bf16x8 afr[4], bfr[4];
#pragma unroll
      for (int mi = 0; mi < 4; ++mi) {
        const int row = wm + mi * 16 + l15;
        const int jj = (kh * 4 + hi) ^ (row & 7);
        afr[mi] = *(const bf16x8*)((const char*)Asm[buf] + row * 128 + jj * 16);
      }
#pragma unroll
      for (int ni = 0; ni < 4; ++ni) {
        const int row = wn + ni * 16 + l15;
        const int jj = (kh * 4 + hi) ^ (row & 7);
        bfr[ni] = *(const bf16x8*)((const char*)Bsm[buf] + row * 128 + jj * 16);
      }
#pragma unroll
      for (int mi = 0; mi < 4; ++mi)
#pragma unroll
        for (int ni = 0; ni < 4; ++ni)
          acc[mi][ni] = __builtin_amdgcn_mfma_f32_16x16x32_bf16(afr[mi], bfr[ni],
                                                                acc[mi][ni], 0, 0, 0);
    }
    if (kt < 7) {
      asm volatile("" ::: "memory");
      __builtin_amdgcn_s_barrier();
    }
  }
#undef STAGE

  float bv[4];
#pragma unroll
  for (int ni = 0; ni < 4; ++ni) bv[ni] = bias[n0 + wn + ni * 16 + l15];
#pragma unroll
  for (int mi = 0; mi < 4; ++mi)
#pragma unroll
    for (int ni = 0; ni < 4; ++ni)
#pragma unroll
      for (int q = 0; q < 4; ++q) {
        // C/D layout: col = lane&15, row = (lane>>4)*4 + q  [m89/m91]
        const int row = m0 + wm + mi * 16 + hi * 4 + q;
        const int col = n0 + wn + ni * 16 + l15;
        float v = acc[mi][ni][q] + bv[ni];
        if ((row & (L_SEQ - 1)) < delta) v = 0.f;
        out[(size_t)row * DMODEL + col] = v;
      }
}

extern "C" void kernel_launch(void* const* d_in, const int* in_sizes, int n_in,
                              void* d_out, int out_size, void* d_ws, size_t ws_size,
                              hipStream_t stream) {
  const float* h    = (const float*)d_in[0];
  const int*   woff = (const int*)d_in[1];
  const float* Wred = (const float*)d_in[2];
  const float* Wrb  = (const float*)d_in[3];
  const float* Wplu = (const float*)d_in[4];
  const float* Wpb  = (const float*)d_in[5];
  float* out = (float*)d_out;

  char* ws = (char*)d_ws;
  float*  z   = (float*)ws;                                    // 4 MB
  __bf16* Aph = (__bf16*)(ws + (4u << 20));                    // 32 MB
  __bf16* Wt  = (__bf16*)(ws + (36u << 20));                   // 1 MB
  __bf16* Bh  = (__bf16*)(ws + (37u << 20));                   // 64 KB
  __bf16* Bl  = (__bf16*)(ws + (37u << 20) + (64u << 10));     // 64 KB

  hipLaunchKernelGGL(kprep,  dim3(192),         dim3(256), 0, stream, Wplu, Wt, Wred, Bh, Bl);
  hipLaunchKernelGGL(kz,     dim3(MROWS / 128), dim3(256), 0, stream, h, Bh, Bl, Wrb, z);
  hipLaunchKernelGGL(kpairs, dim3(MROWS / 4),   dim3(256), 0, stream, z, woff, Aph);
  hipLaunchKernelGGL(kgemm,  dim3(2048),        dim3(256), 0, stream, Aph, Wt, Wpb, woff, out);
}